// Round 4
// baseline (221.924 us; speedup 1.0000x reference)
//
#include <hip/hip_runtime.h>
#include <math.h>

// Problem constants
#define SS    256      // seq len
#define BB    4        // batch
#define HH    160      // hidden
#define NH_   8        // heads
#define HD_   20       // head dim
#define TBL   1025     // 2*MAXLEN+1
#define MAXL  512
#define FF_   640

// ---------------------------------------------------------------------------
// Kernel 1: P tables.  P[tab][row][c] = sum_cp pe_tab[row,cp] * W_fus[tab*H+cp, c]
// b_fus folded into tab 0.   grid (1025, 4), block 160
// ---------------------------------------------------------------------------
__global__ __launch_bounds__(160) void k_ptab(
    const float* __restrict__ pe_ss, const float* __restrict__ pe_se,
    const float* __restrict__ pe_es, const float* __restrict__ pe_ee,
    const float* __restrict__ W_fus, const float* __restrict__ b_fus,
    float* __restrict__ P) {
  int row = blockIdx.x, tab = blockIdx.y, c = threadIdx.x;
  const float* pe = (tab == 0) ? pe_ss : (tab == 1) ? pe_se : (tab == 2) ? pe_es : pe_ee;
  __shared__ __align__(16) float xs[HH];
  xs[c] = pe[row * HH + c];
  __syncthreads();
  float acc = (tab == 0) ? b_fus[c] : 0.0f;
  const float* wcol = W_fus + (size_t)tab * HH * HH + c;
  #pragma unroll 8
  for (int cp = 0; cp < HH; ++cp) acc = fmaf(xs[cp], wcol[cp * HH], acc);
  P[((size_t)tab * TBL + row) * HH + c] = acc;
}

// ---------------------------------------------------------------------------
// Build M[cp][col] (160 x 1280): col = h*160+cc;
// M = (cp/20==h) ? Wr[cc*160+cp] : 0.   Then gmat = qv @ M  gives
// gmat[t][h*160+cc] = sum_d qv[t][20h+d] * Wr[cc*160+20h+d].
// ---------------------------------------------------------------------------
__global__ __launch_bounds__(256) void k_mkM(const float* __restrict__ Wr,
                                             float* __restrict__ M) {
  int o = blockIdx.x * 256 + threadIdx.x;
  if (o >= HH * NH_ * HH) return;
  int cp = o / (NH_ * HH), col = o % (NH_ * HH);
  int h = col / HH, cc = col % HH;
  M[o] = (cp / HD_ == h) ? Wr[(size_t)cc * HH + cp] : 0.0f;
}

// ---------------------------------------------------------------------------
// Generic tiled GEMM: C[M,N] = op(A[M,KK] @ W[KK,N] + bias)
// Block: TT tokens x 64 cols; 256 threads = 64 cols x 4 waves.
// ---------------------------------------------------------------------------
template<int TT, int KK, bool RELU>
__global__ __launch_bounds__(256) void k_gemm(
    const float* __restrict__ A, const float* __restrict__ W,
    const float* __restrict__ bias, float* __restrict__ C, int N) {
  const int TPW = TT / 4;
  int tok0 = blockIdx.x * TT;
  int t = threadIdx.x;
  __shared__ __align__(16) float As[TT][KK];
  {
    const float4* src = (const float4*)(A + (size_t)tok0 * KK);
    float4* dst = (float4*)As;
    for (int idx = t; idx < TT * KK / 4; idx += 256) dst[idx] = src[idx];
  }
  __syncthreads();
  int c = (t & 63) + blockIdx.y * 64;
  int wv = t >> 6;
  if (c < N) {
    float acc[TPW];
    float bb = bias ? bias[c] : 0.0f;
    #pragma unroll
    for (int i = 0; i < TPW; ++i) acc[i] = bb;
    const float* wp = W + c;
    #pragma unroll 2
    for (int k = 0; k < KK; k += 8) {
      float w[8];
      #pragma unroll
      for (int q = 0; q < 8; ++q) w[q] = wp[(size_t)(k + q) * N];
      #pragma unroll
      for (int i = 0; i < TPW; ++i) {
        const float4 a0 = *(const float4*)&As[wv * TPW + i][k];
        const float4 a1 = *(const float4*)&As[wv * TPW + i][k + 4];
        acc[i] = fmaf(a0.x, w[0], acc[i]);
        acc[i] = fmaf(a0.y, w[1], acc[i]);
        acc[i] = fmaf(a0.z, w[2], acc[i]);
        acc[i] = fmaf(a0.w, w[3], acc[i]);
        acc[i] = fmaf(a1.x, w[4], acc[i]);
        acc[i] = fmaf(a1.y, w[5], acc[i]);
        acc[i] = fmaf(a1.z, w[6], acc[i]);
        acc[i] = fmaf(a1.w, w[7], acc[i]);
      }
    }
    #pragma unroll
    for (int i = 0; i < TPW; ++i) {
      float v = RELU ? fmaxf(acc[i], 0.0f) : acc[i];
      C[(size_t)(tok0 + wv * TPW + i) * N + c] = v;
    }
  }
}

// ---------------------------------------------------------------------------
// Fused Q/K/V projection (+ qv = q + vtab).  grid (M/16, 8).
// ---------------------------------------------------------------------------
__global__ __launch_bounds__(256) void k_qkv(
    const float* __restrict__ A,
    const float* __restrict__ Wq, const float* __restrict__ bq,
    const float* __restrict__ Wk, const float* __restrict__ bk,
    const float* __restrict__ Wv, const float* __restrict__ bv,
    const float* __restrict__ vtab,
    float* __restrict__ qb, float* __restrict__ kb, float* __restrict__ vb,
    float* __restrict__ qvb) {
  const int TT = 16, TPW = 4;
  int tok0 = blockIdx.x * TT;
  int t = threadIdx.x;
  __shared__ __align__(16) float As[TT][HH];
  {
    const float4* src = (const float4*)(A + (size_t)tok0 * HH);
    float4* dst = (float4*)As;
    for (int idx = t; idx < TT * HH / 4; idx += 256) dst[idx] = src[idx];
  }
  __syncthreads();
  int col = (t & 63) + blockIdx.y * 64;   // 0..511
  int wv = t >> 6;
  if (col < 480) {
    int mat = col / 160;
    int c = col - mat * 160;
    const float* W   = (mat == 0) ? Wq : (mat == 1) ? Wk : Wv;
    const float* bia = (mat == 0) ? bq : (mat == 1) ? bk : bv;
    float* O         = (mat == 0) ? qb : (mat == 1) ? kb : vb;
    float acc[TPW];
    float bb = bia[c];
    #pragma unroll
    for (int i = 0; i < TPW; ++i) acc[i] = bb;
    const float* wp = W + c;
    #pragma unroll 2
    for (int k = 0; k < HH; k += 8) {
      float w[8];
      #pragma unroll
      for (int q = 0; q < 8; ++q) w[q] = wp[(size_t)(k + q) * HH];
      #pragma unroll
      for (int i = 0; i < TPW; ++i) {
        const float4 a0 = *(const float4*)&As[wv * TPW + i][k];
        const float4 a1 = *(const float4*)&As[wv * TPW + i][k + 4];
        acc[i] = fmaf(a0.x, w[0], acc[i]);
        acc[i] = fmaf(a0.y, w[1], acc[i]);
        acc[i] = fmaf(a0.z, w[2], acc[i]);
        acc[i] = fmaf(a0.w, w[3], acc[i]);
        acc[i] = fmaf(a1.x, w[4], acc[i]);
        acc[i] = fmaf(a1.y, w[5], acc[i]);
        acc[i] = fmaf(a1.z, w[6], acc[i]);
        acc[i] = fmaf(a1.w, w[7], acc[i]);
      }
    }
    float vt = (mat == 0) ? vtab[c] : 0.0f;
    #pragma unroll
    for (int i = 0; i < TPW; ++i) {
      size_t gt = (size_t)(tok0 + wv * TPW + i) * HH + c;
      O[gt] = acc[i];
      if (mat == 0) qvb[gt] = acc[i] + vt;
    }
  }
}

// ---------------------------------------------------------------------------
// Kernel: fused attention.  One block (4 waves) per (b,i).  Barrier-free
// main loop: lane (jj,cg) owns j-row jj of the pass and column chunk cg.
// Per q-step the 4 cg lanes read consecutive float4s of a row (64B segments).
// rel stays in registers; bd partials reduced over cg lanes via shfl_xor.
// A_C computed per-lane for heads 2cg,2cg+1 (c-range [40cg,40cg+40)).
// ---------------------------------------------------------------------------
#define RSTR 164
#define SCS  257

__global__ __launch_bounds__(256) void k_attn(
    const float* __restrict__ qb, const float* __restrict__ kb, const float* __restrict__ vb,
    const float* __restrict__ gmat, const float* __restrict__ P,
    const int* __restrict__ pos_s, const int* __restrict__ pos_e,
    const int* __restrict__ seq_len, const int* __restrict__ lex_num,
    const float* __restrict__ utab, float* __restrict__ attn_out) {
  int blk = blockIdx.x;        // b*S + i
  int b = blk >> 8;
  int i = blk & 255;
  int t = threadIdx.x;
  __shared__ __align__(16) float qu[HH];
  __shared__ __align__(16) float g_s[NH_][RSTR];
  __shared__ __align__(16) float sc[NH_][SCS];
  __shared__ int ps_s[SS], pe_s[SS];

  if (t < HH) qu[t] = qb[(size_t)blk * HH + t] + utab[t];
  {
    const float4* gsrc = (const float4*)(gmat + (size_t)blk * (NH_ * HH));
    #pragma unroll
    for (int r = 0; r < 2; ++r) {
      int idx = r * 256 + t;
      if (idx < NH_ * HH / 4) {
        int h = idx / 40, c4 = idx - h * 40;
        *(float4*)&g_s[h][c4 * 4] = gsrc[idx];
      }
    }
  }
  ps_s[t] = pos_s[b * SS + t];
  pe_s[t] = pos_e[b * SS + t];
  __syncthreads();

  int w = t >> 6, lane = t & 63;
  int jj = lane >> 2, cg = lane & 3;
  int psi = ps_s[i], pei = pe_s[i];
  int limit = seq_len[b] + lex_num[0];
  const float scale = 0.22360679774997896f;  // 1/sqrt(20)

  const float4* P40 = (const float4*)P;
  const float4* P41 = P40 + (size_t)TBL * 40;
  const float4* P42 = P41 + (size_t)TBL * 40;
  const float4* P43 = P42 + (size_t)TBL * 40;
  const float4* kb4 = (const float4*)(kb + (size_t)b * SS * HH);

  for (int pass = 0; pass < 4; ++pass) {
    int j = w * 64 + pass * 16 + jj;
    int psj = ps_s[j], pej = pe_s[j];
    int o0 = (psi - psj + MAXL) * 40 + cg;
    int o1 = (psi - pej + MAXL) * 40 + cg;
    int o2 = (pei - psj + MAXL) * 40 + cg;
    int o3 = (pei - pej + MAXL) * 40 + cg;
    // rel chunk in registers: floats c = 16q + 4cg + e
    float4 rel[10];
    #pragma unroll
    for (int q = 0; q < 10; ++q) {
      float4 a0 = P40[o0 + q * 4];
      float4 a1 = P41[o1 + q * 4];
      float4 a2 = P42[o2 + q * 4];
      float4 a3 = P43[o3 + q * 4];
      rel[q].x = fmaxf(a0.x + a1.x + a2.x + a3.x, 0.0f);
      rel[q].y = fmaxf(a0.y + a1.y + a2.y + a3.y, 0.0f);
      rel[q].z = fmaxf(a0.z + a1.z + a2.z + a3.z, 0.0f);
      rel[q].w = fmaxf(a0.w + a1.w + a2.w + a3.w, 0.0f);
    }
    // bd partials over this lane's 40 columns
    float bd[NH_];
    #pragma unroll
    for (int h = 0; h < NH_; ++h) bd[h] = 0.0f;
    #pragma unroll
    for (int q = 0; q < 10; ++q) {
      int c4 = (q * 4 + cg) * 4;
      #pragma unroll
      for (int h = 0; h < NH_; ++h) {
        float4 g4 = *(const float4*)&g_s[h][c4];
        bd[h] = fmaf(rel[q].x, g4.x, bd[h]);
        bd[h] = fmaf(rel[q].y, g4.y, bd[h]);
        bd[h] = fmaf(rel[q].z, g4.z, bd[h]);
        bd[h] = fmaf(rel[q].w, g4.w, bd[h]);
      }
    }
    // A_C for heads 2cg, 2cg+1 : c in [40cg, 40cg+40)
    float ac0 = 0.0f, ac1 = 0.0f;
    {
      int kbase = j * 40 + 10 * cg;
      #pragma unroll
      for (int m = 0; m < 10; ++m) {
        float4 kv = kb4[kbase + m];
        float4 q4 = *(const float4*)&qu[(10 * cg + m) * 4];
        if (m < 5) {
          ac0 = fmaf(q4.x, kv.x, ac0); ac0 = fmaf(q4.y, kv.y, ac0);
          ac0 = fmaf(q4.z, kv.z, ac0); ac0 = fmaf(q4.w, kv.w, ac0);
        } else {
          ac1 = fmaf(q4.x, kv.x, ac1); ac1 = fmaf(q4.y, kv.y, ac1);
          ac1 = fmaf(q4.z, kv.z, ac1); ac1 = fmaf(q4.w, kv.w, ac1);
        }
      }
    }
    // reduce bd over the 4 cg lanes (full sum lands in every lane)
    #pragma unroll
    for (int h = 0; h < NH_; ++h) {
      bd[h] += __shfl_xor(bd[h], 1);
      bd[h] += __shfl_xor(bd[h], 2);
    }
    float s0, s1;
    if      (cg == 0) { s0 = bd[0]; s1 = bd[1]; }
    else if (cg == 1) { s0 = bd[2]; s1 = bd[3]; }
    else if (cg == 2) { s0 = bd[4]; s1 = bd[5]; }
    else              { s0 = bd[6]; s1 = bd[7]; }
    bool valid = (j < limit);
    sc[2 * cg][j]     = valid ? (s0 + ac0) * scale : -1.0e15f;
    sc[2 * cg + 1][j] = valid ? (s1 + ac1) * scale : -1.0e15f;
  }
  __syncthreads();

  // softmax: 8 groups of 32 lanes, one head each
  {
    int h = t >> 5, l = t & 31;
    float m = -3.0e38f;
    float e[8];
    #pragma unroll
    for (int ii = 0; ii < 8; ++ii) m = fmaxf(m, sc[h][l + ii * 32]);
    #pragma unroll
    for (int msk = 16; msk; msk >>= 1) m = fmaxf(m, __shfl_xor(m, msk));
    float s = 0.0f;
    #pragma unroll
    for (int ii = 0; ii < 8; ++ii) { e[ii] = __expf(sc[h][l + ii * 32] - m); s += e[ii]; }
    #pragma unroll
    for (int msk = 16; msk; msk >>= 1) s += __shfl_xor(s, msk);
    float inv = 1.0f / s;
    #pragma unroll
    for (int ii = 0; ii < 8; ++ii) sc[h][l + ii * 32] = e[ii] * inv;
  }
  __syncthreads();

  // PV: thread c<160 computes out[c]
  if (t < HH) {
    int h = t / HD_;
    float acc0 = 0.f, acc1 = 0.f, acc2 = 0.f, acc3 = 0.f;
    const float* vcol = vb + (size_t)b * SS * HH + t;
    #pragma unroll 2
    for (int j2 = 0; j2 < SS; j2 += 4) {
      acc0 = fmaf(sc[h][j2 + 0], vcol[(size_t)(j2 + 0) * HH], acc0);
      acc1 = fmaf(sc[h][j2 + 1], vcol[(size_t)(j2 + 1) * HH], acc1);
      acc2 = fmaf(sc[h][j2 + 2], vcol[(size_t)(j2 + 2) * HH], acc2);
      acc3 = fmaf(sc[h][j2 + 3], vcol[(size_t)(j2 + 3) * HH], acc3);
    }
    attn_out[(size_t)blk * HH + t] = (acc0 + acc1) + (acc2 + acc3);
  }
}

// ---------------------------------------------------------------------------
// LayerNorm over rows of 160.  LN(y+y) == LN(y) with eps/4.
// ---------------------------------------------------------------------------
__global__ __launch_bounds__(256) void k_ln(
    const float* __restrict__ Y, const float* __restrict__ g,
    const float* __restrict__ bln, float* __restrict__ O) {
  int tok = blockIdx.x * 4 + (threadIdx.x >> 6);
  int l = threadIdx.x & 63;
  const float* y = Y + (size_t)tok * HH;
  float a = y[l];
  float bv = y[l + 64];
  bool has3 = l < (HH - 128);
  float cv = has3 ? y[l + 128] : 0.0f;
  float s = a + bv + cv;
  #pragma unroll
  for (int m = 32; m; m >>= 1) s += __shfl_xor(s, m);
  float mu = s * (1.0f / HH);
  float da = a - mu, db = bv - mu, dc = has3 ? (cv - mu) : 0.0f;
  float s2 = da * da + db * db + dc * dc;
  #pragma unroll
  for (int m = 32; m; m >>= 1) s2 += __shfl_xor(s2, m);
  float rstd = rsqrtf(s2 * (1.0f / HH) + 2.5e-6f);  // eps 1e-5 / 4
  float* o = O + (size_t)tok * HH;
  o[l]      = da * rstd * g[l] + bln[l];
  o[l + 64] = db * rstd * g[l + 64] + bln[l + 64];
  if (has3) o[l + 128] = dc * rstd * g[l + 128] + bln[l + 128];
}

// ---------------------------------------------------------------------------
extern "C" void kernel_launch(void* const* d_in, const int* in_sizes, int n_in,
                              void* d_out, int out_size, void* d_ws, size_t ws_size,
                              hipStream_t stream) {
  const float* inp    = (const float*)d_in[0];
  const int*   pos_s  = (const int*)d_in[1];
  const int*   pos_e  = (const int*)d_in[2];
  const int*   seq_ln = (const int*)d_in[3];
  const int*   lex_nm = (const int*)d_in[4];
  const float* pe_ss  = (const float*)d_in[5];
  const float* pe_se  = (const float*)d_in[6];
  const float* pe_es  = (const float*)d_in[7];
  const float* pe_ee  = (const float*)d_in[8];
  const float* W_fus  = (const float*)d_in[9];
  const float* b_fus  = (const float*)d_in[10];
  const float* Wq     = (const float*)d_in[11];
  const float* bq     = (const float*)d_in[12];
  const float* Wk     = (const float*)d_in[13];
  const float* bk     = (const float*)d_in[14];
  const float* Wv     = (const float*)d_in[15];
  const float* bv     = (const float*)d_in[16];
  const float* Wr     = (const float*)d_in[17];
  // d_in[18] = br : constant-over-j term, cancels in softmax
  const float* utab   = (const float*)d_in[19];
  const float* vtab   = (const float*)d_in[20];
  const float* W_fin  = (const float*)d_in[21];
  const float* b_fin  = (const float*)d_in[22];
  const float* ln1_g  = (const float*)d_in[23];
  const float* ln1_b  = (const float*)d_in[24];
  const float* W1     = (const float*)d_in[25];
  const float* b1     = (const float*)d_in[26];
  const float* W2     = (const float*)d_in[27];
  const float* b2     = (const float*)d_in[28];
  const float* ln2_g  = (const float*)d_in[29];
  const float* ln2_b  = (const float*)d_in[30];

  float* ws = (float*)d_ws;
  // persistent regions
  float* P        = ws;                        // 4*1025*160 = 656000
  float* qb       = P + 4 * TBL * HH;          // 163840 each
  float* kb       = qb + BB * SS * HH;
  float* vb       = kb + BB * SS * HH;
  float* qvb      = vb + BB * SS * HH;
  float* Mbuf     = qvb + BB * SS * HH;        // 160*1280 = 204800
  float* gmat     = Mbuf + HH * NH_ * HH;      // 1024*1280 = 1310720
  float* attn_out = gmat + (size_t)BB * SS * NH_ * HH;
  // gmat region reused after attention:
  float* ybuf     = gmat;                      // 163840
  float* x1       = gmat + 163840;             // 163840
  float* hbuf     = gmat + 327680;             // 655360
  float* y2       = gmat + 983040;             // 163840  (total 1146880 <= 1310720)

  (void)in_sizes; (void)n_in; (void)out_size; (void)ws_size;

  const int M = BB * SS;  // 1024

  k_ptab<<<dim3(TBL, 4), 160, 0, stream>>>(pe_ss, pe_se, pe_es, pe_ee, W_fus, b_fus, P);
  k_mkM<<<(HH * NH_ * HH + 255) / 256, 256, 0, stream>>>(Wr, Mbuf);
  k_qkv<<<dim3(M / 16, 8), 256, 0, stream>>>(inp, Wq, bq, Wk, bk, Wv, bv, vtab,
                                             qb, kb, vb, qvb);
  k_gemm<16, HH, false><<<dim3(M / 16, 20), 256, 0, stream>>>(qvb, Mbuf, nullptr, gmat, NH_ * HH);
  k_attn<<<M, 256, 0, stream>>>(qb, kb, vb, gmat, P, pos_s, pos_e, seq_ln, lex_nm,
                                utab, attn_out);
  k_gemm<8, HH, false><<<dim3(M / 8, 3), 256, 0, stream>>>(attn_out, W_fin, b_fin, ybuf, HH);
  k_ln<<<M / 4, 256, 0, stream>>>(ybuf, ln1_g, ln1_b, x1);
  k_gemm<16, HH, true><<<dim3(M / 16, 10), 256, 0, stream>>>(x1, W1, b1, hbuf, FF_);
  k_gemm<8, FF_, false><<<dim3(M / 8, 3), 256, 0, stream>>>(hbuf, W2, b2, y2, HH);
  k_ln<<<M / 4, 256, 0, stream>>>(y2, ln2_g, ln2_b, (float*)d_out);
}

// Round 5
// 146.303 us; speedup vs baseline: 1.5169x; 1.5169x over previous
//
#include <hip/hip_runtime.h>
#include <math.h>

// Problem constants
#define SS    256      // seq len
#define BB    4        // batch
#define HH    160      // hidden
#define NH_   8        // heads
#define HD_   20       // head dim
#define TBL   1025     // 2*MAXLEN+1
#define MAXL  512
#define FF_   640

// ---------------------------------------------------------------------------
// Kernel 1: P tables.  P[tab][row][c] = sum_cp pe_tab[row,cp] * W_fus[tab*H+cp, c]
// b_fus folded into tab 0.   grid (1025, 4), block 160
// ---------------------------------------------------------------------------
__global__ __launch_bounds__(160) void k_ptab(
    const float* __restrict__ pe_ss, const float* __restrict__ pe_se,
    const float* __restrict__ pe_es, const float* __restrict__ pe_ee,
    const float* __restrict__ W_fus, const float* __restrict__ b_fus,
    float* __restrict__ P) {
  int row = blockIdx.x, tab = blockIdx.y, c = threadIdx.x;
  const float* pe = (tab == 0) ? pe_ss : (tab == 1) ? pe_se : (tab == 2) ? pe_es : pe_ee;
  __shared__ __align__(16) float xs[HH];
  xs[c] = pe[row * HH + c];
  __syncthreads();
  float acc = (tab == 0) ? b_fus[c] : 0.0f;
  const float* wcol = W_fus + (size_t)tab * HH * HH + c;
  #pragma unroll 8
  for (int cp = 0; cp < HH; ++cp) acc = fmaf(xs[cp], wcol[cp * HH], acc);
  P[((size_t)tab * TBL + row) * HH + c] = acc;
}

// ---------------------------------------------------------------------------
// WrT[cp][cc] = Wr[cc][cp]  (160x160 transpose, so gmat reads coalesce)
// ---------------------------------------------------------------------------
__global__ __launch_bounds__(256) void k_wrT(const float* __restrict__ Wr,
                                             float* __restrict__ WrT) {
  int o = blockIdx.x * 256 + threadIdx.x;
  if (o < HH * HH) {
    int cp = o / HH, cc = o - cp * HH;
    WrT[o] = Wr[(size_t)cc * HH + cp];
  }
}

// ---------------------------------------------------------------------------
// gmat[t][h*160+cc] = sum_d qv[t][20h+d] * WrT[(20h+d)*160+cc]
// block = 4 tokens, 256 threads; grid 256.
// ---------------------------------------------------------------------------
__global__ __launch_bounds__(256) void k_gmat(
    const float* __restrict__ qvb, const float* __restrict__ WrT,
    float* __restrict__ gmat) {
  const int T = 4;
  int tok0 = blockIdx.x * T;
  int t = threadIdx.x;
  __shared__ __align__(16) float qs[T][HH];
  {
    const float4* src = (const float4*)(qvb + (size_t)tok0 * HH);
    float4* dst = (float4*)qs;
    for (int idx = t; idx < T * HH / 4; idx += 256) dst[idx] = src[idx];
  }
  __syncthreads();
  #pragma unroll
  for (int r = 0; r < 5; ++r) {
    int p = r * 256 + t;                 // 0..1279
    int h = p / HH, cc = p - h * HH;
    float acc0 = 0.f, acc1 = 0.f, acc2 = 0.f, acc3 = 0.f;
    const float* wp = WrT + (size_t)(h * HD_) * HH + cc;
    #pragma unroll 4
    for (int d = 0; d < HD_; ++d) {
      float w = wp[(size_t)d * HH];
      acc0 = fmaf(qs[0][h * HD_ + d], w, acc0);
      acc1 = fmaf(qs[1][h * HD_ + d], w, acc1);
      acc2 = fmaf(qs[2][h * HD_ + d], w, acc2);
      acc3 = fmaf(qs[3][h * HD_ + d], w, acc3);
    }
    gmat[(size_t)(tok0 + 0) * (NH_ * HH) + p] = acc0;
    gmat[(size_t)(tok0 + 1) * (NH_ * HH) + p] = acc1;
    gmat[(size_t)(tok0 + 2) * (NH_ * HH) + p] = acc2;
    gmat[(size_t)(tok0 + 3) * (NH_ * HH) + p] = acc3;
  }
}

// ---------------------------------------------------------------------------
// Generic tiled GEMM: C[M,N] = op(A[M,KK] @ W[KK,N] + bias)
// Block: TT tokens x 64 cols; 256 threads = 64 cols x 4 waves.
// ---------------------------------------------------------------------------
template<int TT, int KK, bool RELU>
__global__ __launch_bounds__(256) void k_gemm(
    const float* __restrict__ A, const float* __restrict__ W,
    const float* __restrict__ bias, float* __restrict__ C, int N) {
  const int TPW = TT / 4;
  int tok0 = blockIdx.x * TT;
  int t = threadIdx.x;
  __shared__ __align__(16) float As[TT][KK];
  {
    const float4* src = (const float4*)(A + (size_t)tok0 * KK);
    float4* dst = (float4*)As;
    for (int idx = t; idx < TT * KK / 4; idx += 256) dst[idx] = src[idx];
  }
  __syncthreads();
  int c = (t & 63) + blockIdx.y * 64;
  int wv = t >> 6;
  if (c < N) {
    float acc[TPW];
    float bb = bias ? bias[c] : 0.0f;
    #pragma unroll
    for (int i = 0; i < TPW; ++i) acc[i] = bb;
    const float* wp = W + c;
    #pragma unroll 2
    for (int k = 0; k < KK; k += 8) {
      float w[8];
      #pragma unroll
      for (int q = 0; q < 8; ++q) w[q] = wp[(size_t)(k + q) * N];
      #pragma unroll
      for (int i = 0; i < TPW; ++i) {
        const float4 a0 = *(const float4*)&As[wv * TPW + i][k];
        const float4 a1 = *(const float4*)&As[wv * TPW + i][k + 4];
        acc[i] = fmaf(a0.x, w[0], acc[i]);
        acc[i] = fmaf(a0.y, w[1], acc[i]);
        acc[i] = fmaf(a0.z, w[2], acc[i]);
        acc[i] = fmaf(a0.w, w[3], acc[i]);
        acc[i] = fmaf(a1.x, w[4], acc[i]);
        acc[i] = fmaf(a1.y, w[5], acc[i]);
        acc[i] = fmaf(a1.z, w[6], acc[i]);
        acc[i] = fmaf(a1.w, w[7], acc[i]);
      }
    }
    #pragma unroll
    for (int i = 0; i < TPW; ++i) {
      float v = RELU ? fmaxf(acc[i], 0.0f) : acc[i];
      C[(size_t)(tok0 + wv * TPW + i) * N + c] = v;
    }
  }
}

// ---------------------------------------------------------------------------
// Fused Q/K/V projection (+ qv = q + vtab).  grid (M/16, 8).
// ---------------------------------------------------------------------------
__global__ __launch_bounds__(256) void k_qkv(
    const float* __restrict__ A,
    const float* __restrict__ Wq, const float* __restrict__ bq,
    const float* __restrict__ Wk, const float* __restrict__ bk,
    const float* __restrict__ Wv, const float* __restrict__ bv,
    const float* __restrict__ vtab,
    float* __restrict__ qb, float* __restrict__ kb, float* __restrict__ vb,
    float* __restrict__ qvb) {
  const int TT = 16, TPW = 4;
  int tok0 = blockIdx.x * TT;
  int t = threadIdx.x;
  __shared__ __align__(16) float As[TT][HH];
  {
    const float4* src = (const float4*)(A + (size_t)tok0 * HH);
    float4* dst = (float4*)As;
    for (int idx = t; idx < TT * HH / 4; idx += 256) dst[idx] = src[idx];
  }
  __syncthreads();
  int col = (t & 63) + blockIdx.y * 64;   // 0..511
  int wv = t >> 6;
  if (col < 480) {
    int mat = col / 160;
    int c = col - mat * 160;
    const float* W   = (mat == 0) ? Wq : (mat == 1) ? Wk : Wv;
    const float* bia = (mat == 0) ? bq : (mat == 1) ? bk : bv;
    float* O         = (mat == 0) ? qb : (mat == 1) ? kb : vb;
    float acc[TPW];
    float bb = bia[c];
    #pragma unroll
    for (int i = 0; i < TPW; ++i) acc[i] = bb;
    const float* wp = W + c;
    #pragma unroll 2
    for (int k = 0; k < HH; k += 8) {
      float w[8];
      #pragma unroll
      for (int q = 0; q < 8; ++q) w[q] = wp[(size_t)(k + q) * HH];
      #pragma unroll
      for (int i = 0; i < TPW; ++i) {
        const float4 a0 = *(const float4*)&As[wv * TPW + i][k];
        const float4 a1 = *(const float4*)&As[wv * TPW + i][k + 4];
        acc[i] = fmaf(a0.x, w[0], acc[i]);
        acc[i] = fmaf(a0.y, w[1], acc[i]);
        acc[i] = fmaf(a0.z, w[2], acc[i]);
        acc[i] = fmaf(a0.w, w[3], acc[i]);
        acc[i] = fmaf(a1.x, w[4], acc[i]);
        acc[i] = fmaf(a1.y, w[5], acc[i]);
        acc[i] = fmaf(a1.z, w[6], acc[i]);
        acc[i] = fmaf(a1.w, w[7], acc[i]);
      }
    }
    float vt = (mat == 0) ? vtab[c] : 0.0f;
    #pragma unroll
    for (int i = 0; i < TPW; ++i) {
      size_t gt = (size_t)(tok0 + wv * TPW + i) * HH + c;
      O[gt] = acc[i];
      if (mat == 0) qvb[gt] = acc[i] + vt;
    }
  }
}

// ---------------------------------------------------------------------------
// Fused attention.  One block (4 waves) per (b,i).  Immediate-consume gather
// (no rel staging -> low VGPR); __launch_bounds__(256,4) caps VGPR at 128 for
// 4 waves/SIMD.  Lane (jj,cg): 4 cg lanes read consecutive 64B of each row.
// ---------------------------------------------------------------------------
#define RSTR 164
#define SCS  257

__global__ __launch_bounds__(256, 4) void k_attn(
    const float* __restrict__ qb, const float* __restrict__ kb, const float* __restrict__ vb,
    const float* __restrict__ gmat, const float* __restrict__ P,
    const int* __restrict__ pos_s, const int* __restrict__ pos_e,
    const int* __restrict__ seq_len, const int* __restrict__ lex_num,
    const float* __restrict__ utab, float* __restrict__ attn_out) {
  int blk = blockIdx.x;        // b*S + i
  int b = blk >> 8;
  int i = blk & 255;
  int t = threadIdx.x;
  __shared__ __align__(16) float qu[HH];
  __shared__ __align__(16) float g_s[NH_][RSTR];
  __shared__ __align__(16) float sc[NH_][SCS];
  __shared__ int ps_s[SS], pe_s[SS];

  if (t < HH) qu[t] = qb[(size_t)blk * HH + t] + utab[t];
  {
    const float4* gsrc = (const float4*)(gmat + (size_t)blk * (NH_ * HH));
    #pragma unroll
    for (int r = 0; r < 2; ++r) {
      int idx = r * 256 + t;
      if (idx < NH_ * HH / 4) {
        int h = idx / 40, c4 = idx - h * 40;
        *(float4*)&g_s[h][c4 * 4] = gsrc[idx];
      }
    }
  }
  ps_s[t] = pos_s[b * SS + t];
  pe_s[t] = pos_e[b * SS + t];
  __syncthreads();

  int w = t >> 6, lane = t & 63;
  int jj = lane >> 2, cg = lane & 3;
  int psi = ps_s[i], pei = pe_s[i];
  int limit = seq_len[b] + lex_num[0];
  const float scale = 0.22360679774997896f;  // 1/sqrt(20)

  const float4* P40 = (const float4*)P;
  const float4* P41 = P40 + (size_t)TBL * 40;
  const float4* P42 = P41 + (size_t)TBL * 40;
  const float4* P43 = P42 + (size_t)TBL * 40;
  const float4* kb4 = (const float4*)(kb + (size_t)b * SS * HH);

  for (int pass = 0; pass < 4; ++pass) {
    int j = w * 64 + pass * 16 + jj;
    int psj = ps_s[j], pej = pe_s[j];
    int o0 = (psi - psj + MAXL) * 40 + cg;
    int o1 = (psi - pej + MAXL) * 40 + cg;
    int o2 = (pei - psj + MAXL) * 40 + cg;
    int o3 = (pei - pej + MAXL) * 40 + cg;
    float bd[NH_];
    #pragma unroll
    for (int h = 0; h < NH_; ++h) bd[h] = 0.0f;
    // immediate-consume gather: 4 loads -> relu -> 32 FMAs, per q
    #pragma unroll 2
    for (int q = 0; q < 10; ++q) {
      float4 a0 = P40[o0 + q * 4];
      float4 a1 = P41[o1 + q * 4];
      float4 a2 = P42[o2 + q * 4];
      float4 a3 = P43[o3 + q * 4];
      float rl0 = fmaxf(a0.x + a1.x + a2.x + a3.x, 0.0f);
      float rl1 = fmaxf(a0.y + a1.y + a2.y + a3.y, 0.0f);
      float rl2 = fmaxf(a0.z + a1.z + a2.z + a3.z, 0.0f);
      float rl3 = fmaxf(a0.w + a1.w + a2.w + a3.w, 0.0f);
      int c4 = (q * 4 + cg) * 4;
      #pragma unroll
      for (int h = 0; h < NH_; ++h) {
        float4 g4 = *(const float4*)&g_s[h][c4];
        bd[h] = fmaf(rl0, g4.x, bd[h]);
        bd[h] = fmaf(rl1, g4.y, bd[h]);
        bd[h] = fmaf(rl2, g4.z, bd[h]);
        bd[h] = fmaf(rl3, g4.w, bd[h]);
      }
    }
    // A_C for heads 2cg, 2cg+1 : c in [40cg, 40cg+40)
    float ac0 = 0.0f, ac1 = 0.0f;
    {
      int kbase = j * 40 + 10 * cg;
      #pragma unroll
      for (int m = 0; m < 10; ++m) {
        float4 kv = kb4[kbase + m];
        float4 q4 = *(const float4*)&qu[(10 * cg + m) * 4];
        if (m < 5) {
          ac0 = fmaf(q4.x, kv.x, ac0); ac0 = fmaf(q4.y, kv.y, ac0);
          ac0 = fmaf(q4.z, kv.z, ac0); ac0 = fmaf(q4.w, kv.w, ac0);
        } else {
          ac1 = fmaf(q4.x, kv.x, ac1); ac1 = fmaf(q4.y, kv.y, ac1);
          ac1 = fmaf(q4.z, kv.z, ac1); ac1 = fmaf(q4.w, kv.w, ac1);
        }
      }
    }
    // reduce bd over the 4 cg lanes (full sum lands in every lane)
    #pragma unroll
    for (int h = 0; h < NH_; ++h) {
      bd[h] += __shfl_xor(bd[h], 1);
      bd[h] += __shfl_xor(bd[h], 2);
    }
    float s0, s1;
    if      (cg == 0) { s0 = bd[0]; s1 = bd[1]; }
    else if (cg == 1) { s0 = bd[2]; s1 = bd[3]; }
    else if (cg == 2) { s0 = bd[4]; s1 = bd[5]; }
    else              { s0 = bd[6]; s1 = bd[7]; }
    bool valid = (j < limit);
    sc[2 * cg][j]     = valid ? (s0 + ac0) * scale : -1.0e15f;
    sc[2 * cg + 1][j] = valid ? (s1 + ac1) * scale : -1.0e15f;
  }
  __syncthreads();

  // softmax: 8 groups of 32 lanes, one head each
  {
    int h = t >> 5, l = t & 31;
    float m = -3.0e38f;
    float e[8];
    #pragma unroll
    for (int ii = 0; ii < 8; ++ii) m = fmaxf(m, sc[h][l + ii * 32]);
    #pragma unroll
    for (int msk = 16; msk; msk >>= 1) m = fmaxf(m, __shfl_xor(m, msk));
    float s = 0.0f;
    #pragma unroll
    for (int ii = 0; ii < 8; ++ii) { e[ii] = __expf(sc[h][l + ii * 32] - m); s += e[ii]; }
    #pragma unroll
    for (int msk = 16; msk; msk >>= 1) s += __shfl_xor(s, msk);
    float inv = 1.0f / s;
    #pragma unroll
    for (int ii = 0; ii < 8; ++ii) sc[h][l + ii * 32] = e[ii] * inv;
  }
  __syncthreads();

  // PV: thread c<160 computes out[c]
  if (t < HH) {
    int h = t / HD_;
    float acc0 = 0.f, acc1 = 0.f, acc2 = 0.f, acc3 = 0.f;
    const float* vcol = vb + (size_t)b * SS * HH + t;
    #pragma unroll 2
    for (int j2 = 0; j2 < SS; j2 += 4) {
      acc0 = fmaf(sc[h][j2 + 0], vcol[(size_t)(j2 + 0) * HH], acc0);
      acc1 = fmaf(sc[h][j2 + 1], vcol[(size_t)(j2 + 1) * HH], acc1);
      acc2 = fmaf(sc[h][j2 + 2], vcol[(size_t)(j2 + 2) * HH], acc2);
      acc3 = fmaf(sc[h][j2 + 3], vcol[(size_t)(j2 + 3) * HH], acc3);
    }
    attn_out[(size_t)blk * HH + t] = (acc0 + acc1) + (acc2 + acc3);
  }
}

// ---------------------------------------------------------------------------
// LayerNorm over rows of 160.  LN(y+y) == LN(y) with eps/4.
// ---------------------------------------------------------------------------
__global__ __launch_bounds__(256) void k_ln(
    const float* __restrict__ Y, const float* __restrict__ g,
    const float* __restrict__ bln, float* __restrict__ O) {
  int tok = blockIdx.x * 4 + (threadIdx.x >> 6);
  int l = threadIdx.x & 63;
  const float* y = Y + (size_t)tok * HH;
  float a = y[l];
  float bv = y[l + 64];
  bool has3 = l < (HH - 128);
  float cv = has3 ? y[l + 128] : 0.0f;
  float s = a + bv + cv;
  #pragma unroll
  for (int m = 32; m; m >>= 1) s += __shfl_xor(s, m);
  float mu = s * (1.0f / HH);
  float da = a - mu, db = bv - mu, dc = has3 ? (cv - mu) : 0.0f;
  float s2 = da * da + db * db + dc * dc;
  #pragma unroll
  for (int m = 32; m; m >>= 1) s2 += __shfl_xor(s2, m);
  float rstd = rsqrtf(s2 * (1.0f / HH) + 2.5e-6f);  // eps 1e-5 / 4
  float* o = O + (size_t)tok * HH;
  o[l]      = da * rstd * g[l] + bln[l];
  o[l + 64] = db * rstd * g[l + 64] + bln[l + 64];
  if (has3) o[l + 128] = dc * rstd * g[l + 128] + bln[l + 128];
}

// ---------------------------------------------------------------------------
extern "C" void kernel_launch(void* const* d_in, const int* in_sizes, int n_in,
                              void* d_out, int out_size, void* d_ws, size_t ws_size,
                              hipStream_t stream) {
  const float* inp    = (const float*)d_in[0];
  const int*   pos_s  = (const int*)d_in[1];
  const int*   pos_e  = (const int*)d_in[2];
  const int*   seq_ln = (const int*)d_in[3];
  const int*   lex_nm = (const int*)d_in[4];
  const float* pe_ss  = (const float*)d_in[5];
  const float* pe_se  = (const float*)d_in[6];
  const float* pe_es  = (const float*)d_in[7];
  const float* pe_ee  = (const float*)d_in[8];
  const float* W_fus  = (const float*)d_in[9];
  const float* b_fus  = (const float*)d_in[10];
  const float* Wq     = (const float*)d_in[11];
  const float* bq     = (const float*)d_in[12];
  const float* Wk     = (const float*)d_in[13];
  const float* bk     = (const float*)d_in[14];
  const float* Wv     = (const float*)d_in[15];
  const float* bv     = (const float*)d_in[16];
  const float* Wr     = (const float*)d_in[17];
  // d_in[18] = br : constant-over-j term, cancels in softmax
  const float* utab   = (const float*)d_in[19];
  const float* vtab   = (const float*)d_in[20];
  const float* W_fin  = (const float*)d_in[21];
  const float* b_fin  = (const float*)d_in[22];
  const float* ln1_g  = (const float*)d_in[23];
  const float* ln1_b  = (const float*)d_in[24];
  const float* W1     = (const float*)d_in[25];
  const float* b1     = (const float*)d_in[26];
  const float* W2     = (const float*)d_in[27];
  const float* b2     = (const float*)d_in[28];
  const float* ln2_g  = (const float*)d_in[29];
  const float* ln2_b  = (const float*)d_in[30];

  float* ws = (float*)d_ws;
  // persistent regions
  float* P        = ws;                        // 4*1025*160 = 656000
  float* qb       = P + 4 * TBL * HH;          // 163840 each
  float* kb       = qb + BB * SS * HH;
  float* vb       = kb + BB * SS * HH;
  float* qvb      = vb + BB * SS * HH;
  float* WrT      = qvb + BB * SS * HH;        // 25600
  float* gmat     = WrT + HH * HH;             // 1024*1280 = 1310720
  float* attn_out = gmat + (size_t)BB * SS * NH_ * HH;
  // gmat region reused after attention:
  float* ybuf     = gmat;                      // 163840
  float* x1       = gmat + 163840;             // 163840
  float* hbuf     = gmat + 327680;             // 655360
  float* y2       = gmat + 983040;             // 163840  (total 1146880 <= 1310720)

  (void)in_sizes; (void)n_in; (void)out_size; (void)ws_size;

  const int M = BB * SS;  // 1024

  k_ptab<<<dim3(TBL, 4), 160, 0, stream>>>(pe_ss, pe_se, pe_es, pe_ee, W_fus, b_fus, P);
  k_wrT<<<(HH * HH + 255) / 256, 256, 0, stream>>>(Wr, WrT);
  k_qkv<<<dim3(M / 16, 8), 256, 0, stream>>>(inp, Wq, bq, Wk, bk, Wv, bv, vtab,
                                             qb, kb, vb, qvb);
  k_gmat<<<M / 4, 256, 0, stream>>>(qvb, WrT, gmat);
  k_attn<<<M, 256, 0, stream>>>(qb, kb, vb, gmat, P, pos_s, pos_e, seq_ln, lex_nm,
                                utab, attn_out);
  k_gemm<8, HH, false><<<dim3(M / 8, 3), 256, 0, stream>>>(attn_out, W_fin, b_fin, ybuf, HH);
  k_ln<<<M / 4, 256, 0, stream>>>(ybuf, ln1_g, ln1_b, x1);
  k_gemm<16, HH, true><<<dim3(M / 16, 10), 256, 0, stream>>>(x1, W1, b1, hbuf, FF_);
  k_gemm<8, FF_, false><<<dim3(M / 8, 3), 256, 0, stream>>>(hbuf, W2, b2, y2, HH);
  k_ln<<<M / 4, 256, 0, stream>>>(y2, ln2_g, ln2_b, (float*)d_out);
}

// Round 6
// 116.033 us; speedup vs baseline: 1.9126x; 1.2609x over previous
//
#include <hip/hip_runtime.h>
#include <math.h>

// Problem constants
#define SS    256      // seq len
#define BB    4        // batch
#define HH    160      // hidden
#define NH_   8        // heads
#define HD_   20       // head dim
#define TBL   1025     // 2*MAXLEN+1
#define MAXL  512
#define FF_   640

// setup-kernel block ranges
#define PT_TILES 129                   // ceil(1025/8)
#define PT_PER_TAB (PT_TILES * 3)      // 387
#define PT_END (4 * PT_PER_TAB)        // 1548
#define QKV_END (PT_END + 512)         // + (1024/16) x 8
#define WRT_END (QKV_END + 100)        // + 25600/256

// ---------------------------------------------------------------------------
// Mega setup kernel: [0,1548) ptab-as-GEMM; [1548,2060) QKV; [2060,2160) WrT.
// All branches are block-uniform (branch on blockIdx only).
// ---------------------------------------------------------------------------
__global__ __launch_bounds__(256) void k_setup(
    const float* __restrict__ pe_ss, const float* __restrict__ pe_se,
    const float* __restrict__ pe_es, const float* __restrict__ pe_ee,
    const float* __restrict__ W_fus, const float* __restrict__ b_fus,
    const float* __restrict__ inp,
    const float* __restrict__ Wq, const float* __restrict__ bq,
    const float* __restrict__ Wk, const float* __restrict__ bk,
    const float* __restrict__ Wv, const float* __restrict__ bv,
    const float* __restrict__ Wr,
    float* __restrict__ P, float* __restrict__ qb, float* __restrict__ kb,
    float* __restrict__ vb, float* __restrict__ WrT) {
  int bid = blockIdx.x;
  int t = threadIdx.x;
  __shared__ __align__(16) float As[16][HH];

  if (bid < PT_END) {
    // ---- P tables as tiled GEMM: 8 rows x 64 cols per block ----
    int tab = bid / PT_PER_TAB;
    int rem = bid - tab * PT_PER_TAB;
    int tile = rem / 3, yc = rem - tile * 3;
    int row0 = tile * 8;
    const float* pe = (tab == 0) ? pe_ss : (tab == 1) ? pe_se
                    : (tab == 2) ? pe_es : pe_ee;
    for (int idx = t; idx < 8 * 40; idx += 256) {
      int r = idx / 40, c4 = idx - r * 40;
      if (row0 + r < TBL)
        *(float4*)&As[r][c4 * 4] =
            *(const float4*)(pe + (size_t)(row0 + r) * HH + c4 * 4);
    }
    __syncthreads();
    int c = (t & 63) + yc * 64;
    int wv = t >> 6;
    if (c < HH) {
      float acc0, acc1;
      acc0 = acc1 = (tab == 0) ? b_fus[c] : 0.0f;
      const float* wp = W_fus + (size_t)tab * HH * HH + c;
      int r0 = wv * 2, r1 = wv * 2 + 1;
      #pragma unroll 2
      for (int k = 0; k < HH; k += 8) {
        float w[8];
        #pragma unroll
        for (int q = 0; q < 8; ++q) w[q] = wp[(size_t)(k + q) * HH];
        float4 a0 = *(const float4*)&As[r0][k];
        float4 a1 = *(const float4*)&As[r0][k + 4];
        float4 b0 = *(const float4*)&As[r1][k];
        float4 b1_ = *(const float4*)&As[r1][k + 4];
        acc0 = fmaf(a0.x, w[0], acc0); acc0 = fmaf(a0.y, w[1], acc0);
        acc0 = fmaf(a0.z, w[2], acc0); acc0 = fmaf(a0.w, w[3], acc0);
        acc0 = fmaf(a1.x, w[4], acc0); acc0 = fmaf(a1.y, w[5], acc0);
        acc0 = fmaf(a1.z, w[6], acc0); acc0 = fmaf(a1.w, w[7], acc0);
        acc1 = fmaf(b0.x, w[0], acc1); acc1 = fmaf(b0.y, w[1], acc1);
        acc1 = fmaf(b0.z, w[2], acc1); acc1 = fmaf(b0.w, w[3], acc1);
        acc1 = fmaf(b1_.x, w[4], acc1); acc1 = fmaf(b1_.y, w[5], acc1);
        acc1 = fmaf(b1_.z, w[6], acc1); acc1 = fmaf(b1_.w, w[7], acc1);
      }
      if (row0 + r0 < TBL)
        P[((size_t)tab * TBL + row0 + r0) * HH + c] = acc0;
      if (row0 + r1 < TBL)
        P[((size_t)tab * TBL + row0 + r1) * HH + c] = acc1;
    }
  } else if (bid < QKV_END) {
    // ---- fused Q/K/V projection: 16 tokens x 64 cols-of-480 ----
    int qbid = bid - PT_END;
    int bx = qbid & 63, by = qbid >> 6;     // bx: token tile, by: col chunk
    int tok0 = bx * 16;
    {
      const float4* src = (const float4*)(inp + (size_t)tok0 * HH);
      float4* dst = (float4*)As;
      for (int idx = t; idx < 16 * HH / 4; idx += 256) dst[idx] = src[idx];
    }
    __syncthreads();
    int col = (t & 63) + by * 64;           // 0..511
    int wv = t >> 6;
    if (col < 480) {
      int mat = col / 160;
      int c = col - mat * 160;
      const float* W   = (mat == 0) ? Wq : (mat == 1) ? Wk : Wv;
      const float* bia = (mat == 0) ? bq : (mat == 1) ? bk : bv;
      float* O         = (mat == 0) ? qb : (mat == 1) ? kb : vb;
      float acc[4];
      float bb = bia[c];
      #pragma unroll
      for (int i = 0; i < 4; ++i) acc[i] = bb;
      const float* wp = W + c;
      #pragma unroll 2
      for (int k = 0; k < HH; k += 8) {
        float w[8];
        #pragma unroll
        for (int q = 0; q < 8; ++q) w[q] = wp[(size_t)(k + q) * HH];
        #pragma unroll
        for (int i = 0; i < 4; ++i) {
          const float4 a0 = *(const float4*)&As[wv * 4 + i][k];
          const float4 a1 = *(const float4*)&As[wv * 4 + i][k + 4];
          acc[i] = fmaf(a0.x, w[0], acc[i]);
          acc[i] = fmaf(a0.y, w[1], acc[i]);
          acc[i] = fmaf(a0.z, w[2], acc[i]);
          acc[i] = fmaf(a0.w, w[3], acc[i]);
          acc[i] = fmaf(a1.x, w[4], acc[i]);
          acc[i] = fmaf(a1.y, w[5], acc[i]);
          acc[i] = fmaf(a1.z, w[6], acc[i]);
          acc[i] = fmaf(a1.w, w[7], acc[i]);
        }
      }
      #pragma unroll
      for (int i = 0; i < 4; ++i)
        O[(size_t)(tok0 + wv * 4 + i) * HH + c] = acc[i];
    }
  } else {
    // ---- WrT[cp][cc] = Wr[cc][cp] ----
    int o = (bid - QKV_END) * 256 + t;
    int cp = o / HH, cc = o - cp * HH;
    WrT[o] = Wr[(size_t)cc * HH + cp];
  }
}

// ---------------------------------------------------------------------------
// Generic tiled GEMM: C[M,N] = op(A[M,KK] @ W[KK,N] + bias)
// Block: TT tokens x 64 cols; 256 threads = 64 cols x 4 waves.
// ---------------------------------------------------------------------------
template<int TT, int KK, bool RELU>
__global__ __launch_bounds__(256) void k_gemm(
    const float* __restrict__ A, const float* __restrict__ W,
    const float* __restrict__ bias, float* __restrict__ C, int N) {
  const int TPW = TT / 4;
  int tok0 = blockIdx.x * TT;
  int t = threadIdx.x;
  __shared__ __align__(16) float As[TT][KK];
  {
    const float4* src = (const float4*)(A + (size_t)tok0 * KK);
    float4* dst = (float4*)As;
    for (int idx = t; idx < TT * KK / 4; idx += 256) dst[idx] = src[idx];
  }
  __syncthreads();
  int c = (t & 63) + blockIdx.y * 64;
  int wv = t >> 6;
  if (c < N) {
    float acc[TPW];
    float bb = bias ? bias[c] : 0.0f;
    #pragma unroll
    for (int i = 0; i < TPW; ++i) acc[i] = bb;
    const float* wp = W + c;
    #pragma unroll 2
    for (int k = 0; k < KK; k += 8) {
      float w[8];
      #pragma unroll
      for (int q = 0; q < 8; ++q) w[q] = wp[(size_t)(k + q) * N];
      #pragma unroll
      for (int i = 0; i < TPW; ++i) {
        const float4 a0 = *(const float4*)&As[wv * TPW + i][k];
        const float4 a1 = *(const float4*)&As[wv * TPW + i][k + 4];
        acc[i] = fmaf(a0.x, w[0], acc[i]);
        acc[i] = fmaf(a0.y, w[1], acc[i]);
        acc[i] = fmaf(a0.z, w[2], acc[i]);
        acc[i] = fmaf(a0.w, w[3], acc[i]);
        acc[i] = fmaf(a1.x, w[4], acc[i]);
        acc[i] = fmaf(a1.y, w[5], acc[i]);
        acc[i] = fmaf(a1.z, w[6], acc[i]);
        acc[i] = fmaf(a1.w, w[7], acc[i]);
      }
    }
    #pragma unroll
    for (int i = 0; i < TPW; ++i) {
      float v = RELU ? fmaxf(acc[i], 0.0f) : acc[i];
      C[(size_t)(tok0 + wv * TPW + i) * N + c] = v;
    }
  }
}

// ---------------------------------------------------------------------------
// LN1 + W1 + relu fused: A-tile staged, LN'd in LDS (rows resident), GEMM.
// grid (64, 10).  LN(y+y) == LN(y) with eps/4.
// ---------------------------------------------------------------------------
__global__ __launch_bounds__(256) void k_ffn1(
    const float* __restrict__ Y, const float* __restrict__ g1,
    const float* __restrict__ b1ln, const float* __restrict__ W1,
    const float* __restrict__ b1, float* __restrict__ Hb) {
  const int TT = 16;
  int tok0 = blockIdx.x * TT;
  int t = threadIdx.x;
  __shared__ __align__(16) float As[TT][HH];
  {
    const float4* src = (const float4*)(Y + (size_t)tok0 * HH);
    float4* dst = (float4*)As;
    for (int idx = t; idx < TT * HH / 4; idx += 256) dst[idx] = src[idx];
  }
  __syncthreads();
  // LN per row: 16 threads per row (row-exclusive, no extra barrier needed)
  {
    int row = t >> 4, l = t & 15;
    float s = 0.0f;
    #pragma unroll
    for (int c = l; c < HH; c += 16) s += As[row][c];
    #pragma unroll
    for (int m = 1; m < 16; m <<= 1) s += __shfl_xor(s, m);
    float mu = s * (1.0f / HH);
    float s2 = 0.0f;
    #pragma unroll
    for (int c = l; c < HH; c += 16) { float d = As[row][c] - mu; s2 = fmaf(d, d, s2); }
    #pragma unroll
    for (int m = 1; m < 16; m <<= 1) s2 += __shfl_xor(s2, m);
    float rstd = rsqrtf(s2 * (1.0f / HH) + 2.5e-6f);  // eps 1e-5 / 4
    #pragma unroll
    for (int c = l; c < HH; c += 16)
      As[row][c] = (As[row][c] - mu) * rstd * g1[c] + b1ln[c];
  }
  __syncthreads();
  // GEMM -> relu -> Hb
  int c = (t & 63) + blockIdx.y * 64;   // < 640 always
  int wv = t >> 6;
  float acc[4];
  float bb = b1[c];
  #pragma unroll
  for (int i = 0; i < 4; ++i) acc[i] = bb;
  const float* wp = W1 + c;
  #pragma unroll 2
  for (int k = 0; k < HH; k += 8) {
    float w[8];
    #pragma unroll
    for (int q = 0; q < 8; ++q) w[q] = wp[(size_t)(k + q) * FF_];
    #pragma unroll
    for (int i = 0; i < 4; ++i) {
      const float4 a0 = *(const float4*)&As[wv * 4 + i][k];
      const float4 a1 = *(const float4*)&As[wv * 4 + i][k + 4];
      acc[i] = fmaf(a0.x, w[0], acc[i]);
      acc[i] = fmaf(a0.y, w[1], acc[i]);
      acc[i] = fmaf(a0.z, w[2], acc[i]);
      acc[i] = fmaf(a0.w, w[3], acc[i]);
      acc[i] = fmaf(a1.x, w[4], acc[i]);
      acc[i] = fmaf(a1.y, w[5], acc[i]);
      acc[i] = fmaf(a1.z, w[6], acc[i]);
      acc[i] = fmaf(a1.w, w[7], acc[i]);
    }
  }
  #pragma unroll
  for (int i = 0; i < 4; ++i)
    Hb[(size_t)(tok0 + wv * 4 + i) * FF_ + c] = fmaxf(acc[i], 0.0f);
}

// ---------------------------------------------------------------------------
// Fused attention.  One block (4 waves) per (b,i).  g computed in preamble
// (qv = q + vtab; g[h][cc] = sum_d qv[20h+d]*WrT[(20h+d)*160+cc]).
// Immediate-consume coalesced gather; __launch_bounds__(256,4) caps VGPR.
// ---------------------------------------------------------------------------
#define RSTR 164
#define SCS  257

__global__ __launch_bounds__(256, 4) void k_attn(
    const float* __restrict__ qb, const float* __restrict__ kb, const float* __restrict__ vb,
    const float* __restrict__ WrT, const float* __restrict__ P,
    const int* __restrict__ pos_s, const int* __restrict__ pos_e,
    const int* __restrict__ seq_len, const int* __restrict__ lex_num,
    const float* __restrict__ utab, const float* __restrict__ vtab,
    float* __restrict__ attn_out) {
  int blk = blockIdx.x;        // b*S + i
  int b = blk >> 8;
  int i = blk & 255;
  int t = threadIdx.x;
  __shared__ __align__(16) float qu[HH];
  __shared__ __align__(16) float qv_s[HH];
  __shared__ __align__(16) float g_s[NH_][RSTR];
  __shared__ __align__(16) float sc[NH_][SCS];
  __shared__ int ps_s[SS], pe_s[SS];

  if (t < HH) {
    float q = qb[(size_t)blk * HH + t];
    qu[t] = q + utab[t];
    qv_s[t] = q + vtab[t];
  }
  ps_s[t] = pos_s[b * SS + t];
  pe_s[t] = pos_e[b * SS + t];
  __syncthreads();

  // g[h][cc] = sum_d qv[20h+d] * WrT[(20h+d)*160+cc]  (1280 outputs, 5/thread)
  #pragma unroll
  for (int r = 0; r < 5; ++r) {
    int p = r * 256 + t;
    int h = p / HH, cc = p - h * HH;
    const float* wp = WrT + (size_t)(h * HD_) * HH + cc;
    float acc = 0.0f;
    #pragma unroll
    for (int d = 0; d < HD_; ++d)
      acc = fmaf(qv_s[h * HD_ + d], wp[(size_t)d * HH], acc);
    g_s[h][cc] = acc;
  }
  __syncthreads();

  int w = t >> 6, lane = t & 63;
  int jj = lane >> 2, cg = lane & 3;
  int psi = ps_s[i], pei = pe_s[i];
  int limit = seq_len[b] + lex_num[0];
  const float scale = 0.22360679774997896f;  // 1/sqrt(20)

  const float4* P40 = (const float4*)P;
  const float4* P41 = P40 + (size_t)TBL * 40;
  const float4* P42 = P41 + (size_t)TBL * 40;
  const float4* P43 = P42 + (size_t)TBL * 40;
  const float4* kb4 = (const float4*)(kb + (size_t)b * SS * HH);

  for (int pass = 0; pass < 4; ++pass) {
    int j = w * 64 + pass * 16 + jj;
    int psj = ps_s[j], pej = pe_s[j];
    int o0 = (psi - psj + MAXL) * 40 + cg;
    int o1 = (psi - pej + MAXL) * 40 + cg;
    int o2 = (pei - psj + MAXL) * 40 + cg;
    int o3 = (pei - pej + MAXL) * 40 + cg;
    float bd[NH_];
    #pragma unroll
    for (int h = 0; h < NH_; ++h) bd[h] = 0.0f;
    // immediate-consume gather: 4 loads -> relu -> 32 FMAs, per q
    #pragma unroll 2
    for (int q = 0; q < 10; ++q) {
      float4 a0 = P40[o0 + q * 4];
      float4 a1 = P41[o1 + q * 4];
      float4 a2 = P42[o2 + q * 4];
      float4 a3 = P43[o3 + q * 4];
      float rl0 = fmaxf(a0.x + a1.x + a2.x + a3.x, 0.0f);
      float rl1 = fmaxf(a0.y + a1.y + a2.y + a3.y, 0.0f);
      float rl2 = fmaxf(a0.z + a1.z + a2.z + a3.z, 0.0f);
      float rl3 = fmaxf(a0.w + a1.w + a2.w + a3.w, 0.0f);
      int c4 = (q * 4 + cg) * 4;
      #pragma unroll
      for (int h = 0; h < NH_; ++h) {
        float4 g4 = *(const float4*)&g_s[h][c4];
        bd[h] = fmaf(rl0, g4.x, bd[h]);
        bd[h] = fmaf(rl1, g4.y, bd[h]);
        bd[h] = fmaf(rl2, g4.z, bd[h]);
        bd[h] = fmaf(rl3, g4.w, bd[h]);
      }
    }
    // A_C for heads 2cg, 2cg+1 : c in [40cg, 40cg+40)
    float ac0 = 0.0f, ac1 = 0.0f;
    {
      int kbase = j * 40 + 10 * cg;
      #pragma unroll
      for (int m = 0; m < 10; ++m) {
        float4 kv = kb4[kbase + m];
        float4 q4 = *(const float4*)&qu[(10 * cg + m) * 4];
        if (m < 5) {
          ac0 = fmaf(q4.x, kv.x, ac0); ac0 = fmaf(q4.y, kv.y, ac0);
          ac0 = fmaf(q4.z, kv.z, ac0); ac0 = fmaf(q4.w, kv.w, ac0);
        } else {
          ac1 = fmaf(q4.x, kv.x, ac1); ac1 = fmaf(q4.y, kv.y, ac1);
          ac1 = fmaf(q4.z, kv.z, ac1); ac1 = fmaf(q4.w, kv.w, ac1);
        }
      }
    }
    // reduce bd over the 4 cg lanes (full sum lands in every lane)
    #pragma unroll
    for (int h = 0; h < NH_; ++h) {
      bd[h] += __shfl_xor(bd[h], 1);
      bd[h] += __shfl_xor(bd[h], 2);
    }
    float s0, s1;
    if      (cg == 0) { s0 = bd[0]; s1 = bd[1]; }
    else if (cg == 1) { s0 = bd[2]; s1 = bd[3]; }
    else if (cg == 2) { s0 = bd[4]; s1 = bd[5]; }
    else              { s0 = bd[6]; s1 = bd[7]; }
    bool valid = (j < limit);
    sc[2 * cg][j]     = valid ? (s0 + ac0) * scale : -1.0e15f;
    sc[2 * cg + 1][j] = valid ? (s1 + ac1) * scale : -1.0e15f;
  }
  __syncthreads();

  // softmax: 8 groups of 32 lanes, one head each
  {
    int h = t >> 5, l = t & 31;
    float m = -3.0e38f;
    float e[8];
    #pragma unroll
    for (int ii = 0; ii < 8; ++ii) m = fmaxf(m, sc[h][l + ii * 32]);
    #pragma unroll
    for (int msk = 16; msk; msk >>= 1) m = fmaxf(m, __shfl_xor(m, msk));
    float s = 0.0f;
    #pragma unroll
    for (int ii = 0; ii < 8; ++ii) { e[ii] = __expf(sc[h][l + ii * 32] - m); s += e[ii]; }
    #pragma unroll
    for (int msk = 16; msk; msk >>= 1) s += __shfl_xor(s, msk);
    float inv = 1.0f / s;
    #pragma unroll
    for (int ii = 0; ii < 8; ++ii) sc[h][l + ii * 32] = e[ii] * inv;
  }
  __syncthreads();

  // PV: thread c<160 computes out[c]
  if (t < HH) {
    int h = t / HD_;
    float acc0 = 0.f, acc1 = 0.f, acc2 = 0.f, acc3 = 0.f;
    const float* vcol = vb + (size_t)b * SS * HH + t;
    #pragma unroll 2
    for (int j2 = 0; j2 < SS; j2 += 4) {
      acc0 = fmaf(sc[h][j2 + 0], vcol[(size_t)(j2 + 0) * HH], acc0);
      acc1 = fmaf(sc[h][j2 + 1], vcol[(size_t)(j2 + 1) * HH], acc1);
      acc2 = fmaf(sc[h][j2 + 2], vcol[(size_t)(j2 + 2) * HH], acc2);
      acc3 = fmaf(sc[h][j2 + 3], vcol[(size_t)(j2 + 3) * HH], acc3);
    }
    attn_out[(size_t)blk * HH + t] = (acc0 + acc1) + (acc2 + acc3);
  }
}

// ---------------------------------------------------------------------------
// Final LayerNorm.  LN(y+y) == LN(y) with eps/4.
// ---------------------------------------------------------------------------
__global__ __launch_bounds__(256) void k_ln(
    const float* __restrict__ Y, const float* __restrict__ g,
    const float* __restrict__ bln, float* __restrict__ O) {
  int tok = blockIdx.x * 4 + (threadIdx.x >> 6);
  int l = threadIdx.x & 63;
  const float* y = Y + (size_t)tok * HH;
  float a = y[l];
  float bv = y[l + 64];
  bool has3 = l < (HH - 128);
  float cv = has3 ? y[l + 128] : 0.0f;
  float s = a + bv + cv;
  #pragma unroll
  for (int m = 32; m; m >>= 1) s += __shfl_xor(s, m);
  float mu = s * (1.0f / HH);
  float da = a - mu, db = bv - mu, dc = has3 ? (cv - mu) : 0.0f;
  float s2 = da * da + db * db + dc * dc;
  #pragma unroll
  for (int m = 32; m; m >>= 1) s2 += __shfl_xor(s2, m);
  float rstd = rsqrtf(s2 * (1.0f / HH) + 2.5e-6f);  // eps 1e-5 / 4
  float* o = O + (size_t)tok * HH;
  o[l]      = da * rstd * g[l] + bln[l];
  o[l + 64] = db * rstd * g[l + 64] + bln[l + 64];
  if (has3) o[l + 128] = dc * rstd * g[l + 128] + bln[l + 128];
}

// ---------------------------------------------------------------------------
extern "C" void kernel_launch(void* const* d_in, const int* in_sizes, int n_in,
                              void* d_out, int out_size, void* d_ws, size_t ws_size,
                              hipStream_t stream) {
  const float* inp    = (const float*)d_in[0];
  const int*   pos_s  = (const int*)d_in[1];
  const int*   pos_e  = (const int*)d_in[2];
  const int*   seq_ln = (const int*)d_in[3];
  const int*   lex_nm = (const int*)d_in[4];
  const float* pe_ss  = (const float*)d_in[5];
  const float* pe_se  = (const float*)d_in[6];
  const float* pe_es  = (const float*)d_in[7];
  const float* pe_ee  = (const float*)d_in[8];
  const float* W_fus  = (const float*)d_in[9];
  const float* b_fus  = (const float*)d_in[10];
  const float* Wq     = (const float*)d_in[11];
  const float* bq     = (const float*)d_in[12];
  const float* Wk     = (const float*)d_in[13];
  const float* bk     = (const float*)d_in[14];
  const float* Wv     = (const float*)d_in[15];
  const float* bv     = (const float*)d_in[16];
  const float* Wr     = (const float*)d_in[17];
  // d_in[18] = br : constant-over-j term, cancels in softmax
  const float* utab   = (const float*)d_in[19];
  const float* vtab   = (const float*)d_in[20];
  const float* W_fin  = (const float*)d_in[21];
  const float* b_fin  = (const float*)d_in[22];
  const float* ln1_g  = (const float*)d_in[23];
  const float* ln1_b  = (const float*)d_in[24];
  const float* W1     = (const float*)d_in[25];
  const float* b1     = (const float*)d_in[26];
  const float* W2     = (const float*)d_in[27];
  const float* b2     = (const float*)d_in[28];
  const float* ln2_g  = (const float*)d_in[29];
  const float* ln2_b  = (const float*)d_in[30];

  float* ws = (float*)d_ws;
  float* P        = ws;                        // 4*1025*160 = 656000
  float* qb       = P + 4 * TBL * HH;          // 163840 each
  float* kb       = qb + BB * SS * HH;
  float* vb       = kb + BB * SS * HH;
  float* WrT      = vb + BB * SS * HH;         // 25600
  float* attn_out = WrT + HH * HH;             // 163840
  float* ybuf     = attn_out + BB * SS * HH;   // 163840
  float* hbuf     = ybuf + BB * SS * HH;       // 655360
  float* y2       = hbuf + (size_t)BB * SS * FF_;  // 163840

  (void)in_sizes; (void)n_in; (void)out_size; (void)ws_size;

  const int M = BB * SS;  // 1024

  k_setup<<<WRT_END, 256, 0, stream>>>(pe_ss, pe_se, pe_es, pe_ee, W_fus, b_fus,
                                       inp, Wq, bq, Wk, bk, Wv, bv, Wr,
                                       P, qb, kb, vb, WrT);
  k_attn<<<M, 256, 0, stream>>>(qb, kb, vb, WrT, P, pos_s, pos_e, seq_ln, lex_nm,
                                utab, vtab, attn_out);
  k_gemm<4, HH, false><<<dim3(M / 4, 3), 256, 0, stream>>>(attn_out, W_fin, b_fin, ybuf, HH);
  k_ffn1<<<dim3(M / 16, 10), 256, 0, stream>>>(ybuf, ln1_g, ln1_b, W1, b1, hbuf);
  k_gemm<4, FF_, false><<<dim3(M / 4, 3), 256, 0, stream>>>(hbuf, W2, b2, y2, HH);
  k_ln<<<M / 4, 256, 0, stream>>>(y2, ln2_g, ln2_b, (float*)d_out);
}